// Round 1
// baseline (155.914 us; speedup 1.0000x reference)
//
#include <hip/hip_runtime.h>
#include <math.h>

#define NQ   4
#define NH   8
#define NL   2
#define DIM  16   // 2^NQ
#define EMB  32

// ---------------------------------------------------------------------------
// Setup: build per-head 16x16 unitary for the parameterized part of the
// circuit (2 layers of RX/RY/RZ per qubit + CNOT ring). 128 threads:
// thread = (head h, basis column col). Qubit q maps to bit (3-q) of the
// flat index (JAX reshape convention).
// Output layout in ws: Ur[h][j][k] at ws[(h*16+j)*16+k], Ui at ws+2048.
// ---------------------------------------------------------------------------
__global__ void build_unitaries_kernel(const float* __restrict__ params,
                                       float* __restrict__ Uws) {
    int tid = threadIdx.x;          // 0..127
    int h   = tid >> 4;
    int col = tid & 15;

    float re[DIM], im[DIM];
#pragma unroll
    for (int j = 0; j < DIM; ++j) { re[j] = (j == col) ? 1.f : 0.f; im[j] = 0.f; }

    for (int l = 0; l < NL; ++l) {
        for (int q = 0; q < NQ; ++q) {
            const float* p = params + ((h * NL + l) * NQ + q) * 3;
            int m = 1 << (3 - q);
            // RX(p[0]): a0' = c a0 - i s a1 ; a1' = -i s a0 + c a1
            {
                float s, c; __sincosf(0.5f * p[0], &s, &c);
#pragma unroll
                for (int j = 0; j < DIM; ++j) {
                    if (j & m) continue;
                    int j1 = j | m;
                    float r0 = re[j], i0 = im[j], r1 = re[j1], i1 = im[j1];
                    re[j]  = c * r0 + s * i1;
                    im[j]  = c * i0 - s * r1;
                    re[j1] = s * i0 + c * r1;
                    im[j1] = -s * r0 + c * i1;
                }
            }
            // RY(p[1]): real rotation
            {
                float s, c; __sincosf(0.5f * p[1], &s, &c);
#pragma unroll
                for (int j = 0; j < DIM; ++j) {
                    if (j & m) continue;
                    int j1 = j | m;
                    float r0 = re[j], i0 = im[j], r1 = re[j1], i1 = im[j1];
                    re[j]  = c * r0 - s * r1;
                    im[j]  = c * i0 - s * i1;
                    re[j1] = s * r0 + c * r1;
                    im[j1] = s * i0 + c * i1;
                }
            }
            // RZ(p[2]): a0' *= (c - i s) ; a1' *= (c + i s)
            {
                float s, c; __sincosf(0.5f * p[2], &s, &c);
#pragma unroll
                for (int j = 0; j < DIM; ++j) {
                    if (j & m) continue;
                    int j1 = j | m;
                    float r0 = re[j], i0 = im[j], r1 = re[j1], i1 = im[j1];
                    re[j]  = c * r0 + s * i0;
                    im[j]  = c * i0 - s * r0;
                    re[j1] = c * r1 - s * i1;
                    im[j1] = c * i1 + s * r1;
                }
            }
        }
        // CNOT ring: (0,1),(1,2),(2,3),(3,0)
#pragma unroll
        for (int e = 0; e < NQ; ++e) {
            int cq = e, tq = (e + 1) & 3;
            int cm = 1 << (3 - cq), tm = 1 << (3 - tq);
#pragma unroll
            for (int j = 0; j < DIM; ++j) {
                if ((j & cm) && !(j & tm)) {
                    int j1 = j | tm;
                    float tr = re[j]; re[j] = re[j1]; re[j1] = tr;
                    float ti = im[j]; im[j] = im[j1]; im[j1] = ti;
                }
            }
        }
    }
#pragma unroll
    for (int j = 0; j < DIM; ++j) {
        Uws[(h * DIM + j) * DIM + col]        = re[j];
        Uws[2048 + (h * DIM + j) * DIM + col] = im[j];
    }
}

// ---------------------------------------------------------------------------
// Main: one thread per token. Per head: build product state psi0 from 4
// half-angle sincos, dense complex matvec with the precomputed unitary
// (wave-uniform s_load expected for Uws/W/b), probabilities, signed Z sums,
// and incremental fold of W_out into 32 output accumulators (all static
// register indices — no scratch).
// ---------------------------------------------------------------------------
__global__ __launch_bounds__(256)
void qmha_kernel(const float* __restrict__ x,
                 const float* __restrict__ Uws,
                 const float* __restrict__ W,
                 const float* __restrict__ bvec,
                 float* __restrict__ out,
                 int ntok) {
    int tok = blockIdx.x * blockDim.x + threadIdx.x;
    if (tok >= ntok) return;

    float oacc[EMB];
#pragma unroll
    for (int e = 0; e < EMB; ++e) oacc[e] = bvec[e];

#pragma unroll 1
    for (int h = 0; h < NH; ++h) {
        const float4 xa = *(const float4*)(x + (size_t)tok * EMB + h * NQ);
        float c0, s0, c1, s1, c2, s2, c3, s3;
        __sincosf(0.5f * xa.x, &s0, &c0);
        __sincosf(0.5f * xa.y, &s1, &c1);
        __sincosf(0.5f * xa.z, &s2, &c2);
        __sincosf(0.5f * xa.w, &s3, &c3);

        // psi0[j] = f0[b3] f1[b2] f2[b1] f3[b0], qubit q <-> bit (3-q)
        float p01[4], p23[4], a[DIM];
        p01[0] = c0 * c1; p01[1] = c0 * s1; p01[2] = s0 * c1; p01[3] = s0 * s1;
        p23[0] = c2 * c3; p23[1] = c2 * s3; p23[2] = s2 * c3; p23[3] = s2 * s3;
#pragma unroll
        for (int j = 0; j < DIM; ++j) a[j] = p01[j >> 2] * p23[j & 3];

        const float* Ur = Uws + h * 256;
        const float* Ui = Uws + 2048 + h * 256;

        float p[DIM];
#pragma unroll
        for (int j = 0; j < DIM; ++j) {
            float ar = 0.f, ai = 0.f;
#pragma unroll
            for (int k = 0; k < DIM; ++k) {
                ar = fmaf(Ur[j * DIM + k], a[k], ar);
                ai = fmaf(Ui[j * DIM + k], a[k], ai);
            }
            p[j] = ar * ar + ai * ai;
        }

        // Z expvals: qubit i <-> bit (3-i)
        float ev0 = 0.f, ev1 = 0.f, ev2 = 0.f, ev3 = 0.f;
#pragma unroll
        for (int j = 0; j < DIM; ++j) {
            ev0 += (j & 8) ? -p[j] : p[j];
            ev1 += (j & 4) ? -p[j] : p[j];
            ev2 += (j & 2) ? -p[j] : p[j];
            ev3 += (j & 1) ? -p[j] : p[j];
        }

        // fold W_out columns for this head into the 32 output accumulators
#pragma unroll
        for (int e = 0; e < EMB; ++e) {
            const float* wc = W + e * EMB + h * NQ;
            oacc[e] = fmaf(wc[0], ev0,
                      fmaf(wc[1], ev1,
                      fmaf(wc[2], ev2,
                      fmaf(wc[3], ev3, oacc[e]))));
        }
    }

    float4* op = (float4*)(out + (size_t)tok * EMB);
#pragma unroll
    for (int i = 0; i < 8; ++i) {
        float4 v;
        v.x = oacc[4 * i + 0];
        v.y = oacc[4 * i + 1];
        v.z = oacc[4 * i + 2];
        v.w = oacc[4 * i + 3];
        op[i] = v;
    }
}

extern "C" void kernel_launch(void* const* d_in, const int* in_sizes, int n_in,
                              void* d_out, int out_size, void* d_ws, size_t ws_size,
                              hipStream_t stream) {
    const float* x      = (const float*)d_in[0];
    const float* params = (const float*)d_in[1];
    const float* W_out  = (const float*)d_in[2];
    const float* b_out  = (const float*)d_in[3];
    float*       out    = (float*)d_out;
    float*       Uws    = (float*)d_ws;   // 4096 floats = 16 KB

    const int ntok = in_sizes[0] / EMB;   // B*S = 131072

    hipLaunchKernelGGL(build_unitaries_kernel, dim3(1), dim3(128), 0, stream,
                       params, Uws);

    const int threads = 256;
    const int blocks  = (ntok + threads - 1) / threads;
    hipLaunchKernelGGL(qmha_kernel, dim3(blocks), dim3(threads), 0, stream,
                       x, Uws, W_out, b_out, out, ntok);
}

// Round 2
// 92.566 us; speedup vs baseline: 1.6843x; 1.6843x over previous
//
#include <hip/hip_runtime.h>
#include <math.h>

#define NQ   4
#define NH   8
#define NL   2
#define DIM  16   // 2^NQ
#define EMB  32
#define TPB  64   // tokens per block

// ---------------------------------------------------------------------------
// Setup: per-head 16x16 unitary for the parameterized circuit. 128 threads:
// (head h, basis column col). Qubit q <-> bit (3-q).
// ALL loops fully unrolled so register indices are static (round-1 version
// had dynamic `m` -> dynamic register indexing -> scratch spills).
// Layout: Ur[h][j][k] at ws[(h*16+j)*16+k], Ui at ws+2048.
// ---------------------------------------------------------------------------
__global__ void build_unitaries_kernel(const float* __restrict__ params,
                                       float* __restrict__ Uws) {
    int tid = threadIdx.x;          // 0..127
    int h   = tid >> 4;
    int col = tid & 15;

    float re[DIM], im[DIM];
#pragma unroll
    for (int j = 0; j < DIM; ++j) { re[j] = (j == col) ? 1.f : 0.f; im[j] = 0.f; }

#pragma unroll
    for (int l = 0; l < NL; ++l) {
#pragma unroll
        for (int q = 0; q < NQ; ++q) {
            const float* p = params + ((h * NL + l) * NQ + q) * 3;
            const int m = 1 << (3 - q);      // compile-time after unroll
            // RX
            {
                float s, c; __sincosf(0.5f * p[0], &s, &c);
#pragma unroll
                for (int j = 0; j < DIM; ++j) {
                    if (j & m) continue;
                    const int j1 = j | m;
                    float r0 = re[j], i0 = im[j], r1 = re[j1], i1 = im[j1];
                    re[j]  = c * r0 + s * i1;
                    im[j]  = c * i0 - s * r1;
                    re[j1] = s * i0 + c * r1;
                    im[j1] = -s * r0 + c * i1;
                }
            }
            // RY
            {
                float s, c; __sincosf(0.5f * p[1], &s, &c);
#pragma unroll
                for (int j = 0; j < DIM; ++j) {
                    if (j & m) continue;
                    const int j1 = j | m;
                    float r0 = re[j], i0 = im[j], r1 = re[j1], i1 = im[j1];
                    re[j]  = c * r0 - s * r1;
                    im[j]  = c * i0 - s * i1;
                    re[j1] = s * r0 + c * r1;
                    im[j1] = s * i0 + c * i1;
                }
            }
            // RZ
            {
                float s, c; __sincosf(0.5f * p[2], &s, &c);
#pragma unroll
                for (int j = 0; j < DIM; ++j) {
                    if (j & m) continue;
                    const int j1 = j | m;
                    float r0 = re[j], i0 = im[j], r1 = re[j1], i1 = im[j1];
                    re[j]  = c * r0 + s * i0;
                    im[j]  = c * i0 - s * r0;
                    re[j1] = c * r1 - s * i1;
                    im[j1] = c * i1 + s * r1;
                }
            }
        }
        // CNOT ring: (0,1),(1,2),(2,3),(3,0)
#pragma unroll
        for (int e = 0; e < NQ; ++e) {
            const int cm = 1 << (3 - e), tm = 1 << (3 - ((e + 1) & 3));
#pragma unroll
            for (int j = 0; j < DIM; ++j) {
                if ((j & cm) && !(j & tm)) {
                    const int j1 = j | tm;
                    float tr = re[j]; re[j] = re[j1]; re[j1] = tr;
                    float ti = im[j]; im[j] = im[j1]; im[j1] = ti;
                }
            }
        }
    }
#pragma unroll
    for (int j = 0; j < DIM; ++j) {
        Uws[(h * DIM + j) * DIM + col]        = re[j];
        Uws[2048 + (h * DIM + j) * DIM + col] = im[j];
    }
}

// ---------------------------------------------------------------------------
// Main: block = 512 threads = 8 waves; wave w handles head w for 64 tokens.
// h is wave-uniform (readfirstlane) -> U reads scalarize to constant-cache
// s_loads. Phase 1: per-(head,token) ev[4] -> LDS evs[k][t] (stride 64:
// writes 2-way/free, reads 8-bank broadcast/free). Phase 2: thread (t2,eg)
// computes out[tok0+t2][eg*4..+3] from LDS ev row and LDS-transposed W
// (stride 36 -> 16B-aligned conflict-free ds_read_b128), stores contiguous
// float4 (wave store fully coalesced).
// ---------------------------------------------------------------------------
__global__ __launch_bounds__(512, 4)
void qmha_kernel(const float* __restrict__ x,
                 const float* __restrict__ Uws,
                 const float* __restrict__ W,
                 const float* __restrict__ bvec,
                 float* __restrict__ out,
                 int ntok) {
    __shared__ float evs[EMB * TPB];   // evs[k][t], k = h*4+q, stride 64
    __shared__ float Wt[EMB * 36];     // Wt[k][e],  stride 36

    const int tid  = threadIdx.x;
    const int tok0 = blockIdx.x * TPB;

    // ---- stage W transposed into LDS: Wt[k][e] = W[e][k] ----
    {
        const int idx = tid * 2;               // 0..1022
        const float2 w2 = *(const float2*)(W + idx);
        const int e0 = idx >> 5, k0 = idx & 31;
        const int e1 = (idx + 1) >> 5, k1 = (idx + 1) & 31;
        Wt[k0 * 36 + e0] = w2.x;
        Wt[k1 * 36 + e1] = w2.y;
    }

    // ---- phase 1: quantum circuit per (head, token) ----
    {
        int h = __builtin_amdgcn_readfirstlane(tid >> 6);  // wave-uniform head
        const int t = tid & 63;
        const int tok = tok0 + t;
        if (tok < ntok) {
            const float4 xa = *(const float4*)(x + (size_t)tok * EMB + h * NQ);
            float c0, s0, c1, s1, c2, s2, c3, s3;
            __sincosf(0.5f * xa.x, &s0, &c0);
            __sincosf(0.5f * xa.y, &s1, &c1);
            __sincosf(0.5f * xa.z, &s2, &c2);
            __sincosf(0.5f * xa.w, &s3, &c3);

            // psi0[j] = f0[b3] f1[b2] f2[b1] f3[b0]
            float p01[4], p23[4], a[DIM];
            p01[0] = c0 * c1; p01[1] = c0 * s1; p01[2] = s0 * c1; p01[3] = s0 * s1;
            p23[0] = c2 * c3; p23[1] = c2 * s3; p23[2] = s2 * c3; p23[3] = s2 * s3;
#pragma unroll
            for (int j = 0; j < DIM; ++j) a[j] = p01[j >> 2] * p23[j & 3];

            const float* Ur = Uws + h * 256;
            const float* Ui = Uws + 2048 + h * 256;

            float ev0 = 0.f, ev1 = 0.f, ev2 = 0.f, ev3 = 0.f;
#pragma unroll
            for (int j = 0; j < DIM; ++j) {
                float ar = 0.f, ai = 0.f;
#pragma unroll
                for (int k = 0; k < DIM; ++k) {
                    ar = fmaf(Ur[j * DIM + k], a[k], ar);
                    ai = fmaf(Ui[j * DIM + k], a[k], ai);
                }
                const float pj = ar * ar + ai * ai;
                ev0 += (j & 8) ? -pj : pj;
                ev1 += (j & 4) ? -pj : pj;
                ev2 += (j & 2) ? -pj : pj;
                ev3 += (j & 1) ? -pj : pj;
            }

            evs[(h * 4 + 0) * TPB + t] = ev0;
            evs[(h * 4 + 1) * TPB + t] = ev1;
            evs[(h * 4 + 2) * TPB + t] = ev2;
            evs[(h * 4 + 3) * TPB + t] = ev3;
        }
    }
    __syncthreads();

    // ---- phase 2: out[tok][e] = b[e] + sum_k ev[tok][k] * W[e][k] ----
    {
        const int t2 = tid >> 3;       // 0..63
        const int eg = tid & 7;        // 0..7 -> outputs eg*4..+3
        const int tok = tok0 + t2;
        if (tok < ntok) {
            const float4 bv = *(const float4*)(bvec + eg * 4);
            float o0 = bv.x, o1 = bv.y, o2 = bv.z, o3 = bv.w;
#pragma unroll
            for (int k = 0; k < EMB; ++k) {
                const float evk = evs[k * TPB + t2];
                const float4 wk = *(const float4*)(Wt + k * 36 + eg * 4);
                o0 = fmaf(wk.x, evk, o0);
                o1 = fmaf(wk.y, evk, o1);
                o2 = fmaf(wk.z, evk, o2);
                o3 = fmaf(wk.w, evk, o3);
            }
            float4 v; v.x = o0; v.y = o1; v.z = o2; v.w = o3;
            *(float4*)(out + (size_t)tok * EMB + eg * 4) = v;
        }
    }
}

extern "C" void kernel_launch(void* const* d_in, const int* in_sizes, int n_in,
                              void* d_out, int out_size, void* d_ws, size_t ws_size,
                              hipStream_t stream) {
    const float* x      = (const float*)d_in[0];
    const float* params = (const float*)d_in[1];
    const float* W_out  = (const float*)d_in[2];
    const float* b_out  = (const float*)d_in[3];
    float*       out    = (float*)d_out;
    float*       Uws    = (float*)d_ws;   // 4096 floats = 16 KB

    const int ntok = in_sizes[0] / EMB;   // B*S = 131072

    hipLaunchKernelGGL(build_unitaries_kernel, dim3(1), dim3(128), 0, stream,
                       params, Uws);

    const int blocks = (ntok + TPB - 1) / TPB;
    hipLaunchKernelGGL(qmha_kernel, dim3(blocks), dim3(512), 0, stream,
                       x, Uws, W_out, b_out, out, ntok);
}